// Round 2
// baseline (130.430 us; speedup 1.0000x reference)
//
#include <hip/hip_runtime.h>

// CBOWSubword: out[t,:] = W[seq[t],:] + W[pre[t],:] + W[post[t],:]
// B*S = 131072 tokens, D = 128 fp32 (= 32 float4 per row).
// Mapping: 32 threads per token, one float4 per thread per row.
//
// Memory-bound random gather. Key insight (R1): the 51 MB weight table has
// ~3.9x average row reuse, but the 64 MiB streaming output stores thrash
// L2 (8 MB stores/XCD vs 4 MB L2/XCD) and pollute L3, evicting table rows
// between reuses -> FETCH_SIZE was 96 MB vs ~53 MB ideal.
// Fix: non-temporal (no-allocate) stores for out, non-temporal loads for
// the once-streamed index arrays; keep weight loads cached.
//
// NOTE: __builtin_nontemporal_* requires a native clang vector type, not
// HIP_vector_type<float,4> -> use ext_vector_type(4) alias (same layout).

#define D4 32  // 128 floats / 4 per float4

typedef float fvec4 __attribute__((ext_vector_type(4)));

__global__ __launch_bounds__(256) void cbow_gather3_kernel(
    const int* __restrict__ seq,
    const int* __restrict__ pre,
    const int* __restrict__ post,
    const fvec4* __restrict__ weight,
    fvec4* __restrict__ out,
    int n_tokens)
{
    int tid = blockIdx.x * blockDim.x + threadIdx.x;
    int token = tid >> 5;      // 32 threads per token
    int lane  = tid & 31;      // which float4 of the 128-float row
    if (token >= n_tokens) return;

    // Index arrays are streamed exactly once -> non-temporal (don't cache).
    int s = __builtin_nontemporal_load(seq  + token);
    int p = __builtin_nontemporal_load(pre  + token);
    int q = __builtin_nontemporal_load(post + token);

    // Weight rows have ~3.9x reuse -> normal cached loads.
    fvec4 a = weight[(size_t)s * D4 + lane];
    fvec4 b = weight[(size_t)p * D4 + lane];
    fvec4 c = weight[(size_t)q * D4 + lane];

    fvec4 r = a + b + c;

    // Output is write-once, never re-read -> non-temporal store so it does
    // not allocate in L2/L3 and evict the weight table between row reuses.
    __builtin_nontemporal_store(r, &out[(size_t)token * D4 + lane]);
}

extern "C" void kernel_launch(void* const* d_in, const int* in_sizes, int n_in,
                              void* d_out, int out_size, void* d_ws, size_t ws_size,
                              hipStream_t stream)
{
    const int*   seq    = (const int*)d_in[0];
    const int*   pre    = (const int*)d_in[1];
    const int*   post   = (const int*)d_in[2];
    const fvec4* weight = (const fvec4*)d_in[3];
    fvec4*       out    = (fvec4*)d_out;

    const int n_tokens = in_sizes[0];          // 128*1024 = 131072
    const long total_threads = (long)n_tokens * 32;
    const int block = 256;
    const int grid = (int)((total_threads + block - 1) / block);

    cbow_gather3_kernel<<<grid, block, 0, stream>>>(seq, pre, post, weight, out, n_tokens);
}

// Round 3
// 125.513 us; speedup vs baseline: 1.0392x; 1.0392x over previous
//
#include <hip/hip_runtime.h>

// CBOWSubword: out[t,:] = W[seq[t],:] + W[pre[t],:] + W[post[t],:]
// B*S = 131072 tokens, D = 128 fp32 (= 32 float4 per row).
//
// Memory-bound random gather + streaming write.
// R1 post-mortem: NT stores did NOT cut FETCH_SIZE (95.9->94.5 MB) and
// slightly hurt (42.9->45 us) -> reverted. The ~1.8x fetch amplification
// vs the 51 MB table is cross-XCD L2 duplication (8 private L2s, random
// rows) -- structural for random indices.
// R2 theory: at 3.6 TB/s vs 6.4 TB/s streaming, the random 512B-granule
// read stream may be HBM-queue/concurrency limited. Double per-thread MLP:
// 2 tokens/thread -> 6 independent gathers in flight per thread, half the
// waves, one index-wait amortized over two tokens.

#define D4 32  // 128 floats / 4 per float4

__global__ __launch_bounds__(256) void cbow_gather3_kernel(
    const int* __restrict__ seq,
    const int* __restrict__ pre,
    const int* __restrict__ post,
    const float4* __restrict__ weight,
    float4* __restrict__ out,
    int n_tokens)
{
    int tid  = blockIdx.x * blockDim.x + threadIdx.x;
    int pair = tid >> 5;       // each 32-lane group handles tokens 2k, 2k+1
    int lane = tid & 31;       // which float4 of the 128-float row
    int t0 = pair * 2;
    if (t0 >= n_tokens) return;
    int t1 = t0 + 1;           // n_tokens is even (131072)

    // 6 index loads issue together (one vmcnt wait covers all).
    int s0 = seq[t0], p0 = pre[t0], q0 = post[t0];
    int s1 = seq[t1], p1 = pre[t1], q1 = post[t1];

    // 6 independent 16B gathers in flight per thread.
    float4 a0 = weight[(size_t)s0 * D4 + lane];
    float4 b0 = weight[(size_t)p0 * D4 + lane];
    float4 c0 = weight[(size_t)q0 * D4 + lane];
    float4 a1 = weight[(size_t)s1 * D4 + lane];
    float4 b1 = weight[(size_t)p1 * D4 + lane];
    float4 c1 = weight[(size_t)q1 * D4 + lane];

    float4 r0, r1;
    r0.x = a0.x + b0.x + c0.x;  r0.y = a0.y + b0.y + c0.y;
    r0.z = a0.z + b0.z + c0.z;  r0.w = a0.w + b0.w + c0.w;
    r1.x = a1.x + b1.x + c1.x;  r1.y = a1.y + b1.y + c1.y;
    r1.z = a1.z + b1.z + c1.z;  r1.w = a1.w + b1.w + c1.w;

    out[(size_t)t0 * D4 + lane] = r0;
    out[(size_t)t1 * D4 + lane] = r1;
}

extern "C" void kernel_launch(void* const* d_in, const int* in_sizes, int n_in,
                              void* d_out, int out_size, void* d_ws, size_t ws_size,
                              hipStream_t stream)
{
    const int*    seq    = (const int*)d_in[0];
    const int*    pre    = (const int*)d_in[1];
    const int*    post   = (const int*)d_in[2];
    const float4* weight = (const float4*)d_in[3];
    float4*       out    = (float4*)d_out;

    const int n_tokens = in_sizes[0];          // 128*1024 = 131072
    const long n_pairs = (n_tokens + 1) / 2;
    const long total_threads = n_pairs * 32;
    const int block = 256;
    const int grid = (int)((total_threads + block - 1) / block);

    cbow_gather3_kernel<<<grid, block, 0, stream>>>(seq, pre, post, weight, out, n_tokens);
}